// Round 1
// baseline (652.145 us; speedup 1.0000x reference)
//
#include <hip/hip_runtime.h>
#include <stdint.h>

#define B_ 8
#define T_ 2048
#define C_ 1024
#define E_ 8
#define K_ 2
#define CAP_ 320
#define DFF_ 4096
#define S_ (T_*K_)          // 4096 assignments per batch row
#define NTOK (B_*T_)        // 16384 tokens
#define ROWS_PER_E (B_*CAP_) // 2560

typedef __attribute__((ext_vector_type(8))) short short8;
typedef __attribute__((ext_vector_type(4))) float floatx4;

__device__ __forceinline__ unsigned short f2bf(float f) {
  union { float f; unsigned u; } v; v.f = f;
  unsigned r = v.u + 0x7fffu + ((v.u >> 16) & 1u);
  return (unsigned short)(r >> 16);
}
__device__ __forceinline__ float bf2f(unsigned short h) {
  union { unsigned u; float f; } v; v.u = ((unsigned)h) << 16;
  return v.f;
}

// ---------------- Router: fp64 logits, softmax, top-2 ----------------
__global__ void router_kernel(const float* __restrict__ x, const float* __restrict__ Wg,
                              const float* __restrict__ bg,
                              int* __restrict__ topk_e, float* __restrict__ topk_p)
{
  int token = (int)((blockIdx.x * blockDim.x + threadIdx.x) >> 6);
  int lane = threadIdx.x & 63;
  if (token >= NTOK) return;
  const float* xr = x + (size_t)token * C_;
  double acc[E_];
  #pragma unroll
  for (int e = 0; e < E_; ++e) acc[e] = 0.0;
  for (int c = lane; c < C_; c += 64) {
    double xv = (double)xr[c];
    const float4* w4 = (const float4*)(Wg + (size_t)c * E_);
    float4 wa = w4[0], wb = w4[1];
    acc[0] += xv * (double)wa.x; acc[1] += xv * (double)wa.y;
    acc[2] += xv * (double)wa.z; acc[3] += xv * (double)wa.w;
    acc[4] += xv * (double)wb.x; acc[5] += xv * (double)wb.y;
    acc[6] += xv * (double)wb.z; acc[7] += xv * (double)wb.w;
  }
  #pragma unroll
  for (int off = 32; off; off >>= 1) {
    #pragma unroll
    for (int e = 0; e < E_; ++e) acc[e] += __shfl_down(acc[e], off, 64);
  }
  if (lane == 0) {
    double lg[E_];
    double mx = -1e300;
    #pragma unroll
    for (int e = 0; e < E_; ++e) { lg[e] = acc[e] + (double)bg[e]; mx = fmax(mx, lg[e]); }
    double se = 0.0, pr[E_];
    #pragma unroll
    for (int e = 0; e < E_; ++e) { pr[e] = exp(lg[e] - mx); se += pr[e]; }
    #pragma unroll
    for (int e = 0; e < E_; ++e) pr[e] /= se;
    int e0 = 0;
    #pragma unroll
    for (int e = 1; e < E_; ++e) if (pr[e] > pr[e0]) e0 = e;
    int e1 = -1;
    #pragma unroll
    for (int e = 0; e < E_; ++e) {
      if (e == e0) continue;
      if (e1 < 0 || pr[e] > pr[e1]) e1 = e;
    }
    topk_e[token*2+0] = e0; topk_p[token*2+0] = (float)pr[e0];
    topk_e[token*2+1] = e1; topk_p[token*2+1] = (float)pr[e1];
  }
}

// ---------------- Scan: per-(b,e) positions, capacity, slot map ----------------
__global__ void scan_kernel(const int* __restrict__ topk_e,
                            int* __restrict__ pos_arr,   // [B_*S_], -1 if dropped
                            int* __restrict__ slot_src,  // [E_*B_*CAP_] -> src token t
                            int* __restrict__ counts)    // [E_*B_]
{
  const int b = blockIdx.x;
  const int tid = threadIdx.x;
  const int PT = S_ / 256; // 16
  __shared__ int cnt[256][E_];
  int e_loc[16];
  int local[E_];
  #pragma unroll
  for (int e = 0; e < E_; ++e) local[e] = 0;
  const int* te = topk_e + (size_t)b * S_;
  for (int j = 0; j < PT; ++j) {
    int e = te[tid*PT + j];
    e_loc[j] = e;
    local[e]++;
  }
  #pragma unroll
  for (int e = 0; e < E_; ++e) cnt[tid][e] = local[e];
  __syncthreads();
  if (tid < E_) {
    int run = 0;
    for (int i = 0; i < 256; ++i) { int v = cnt[i][tid]; cnt[i][tid] = run; run += v; }
    counts[tid*B_ + b] = run;   // counts[e][b]
  }
  __syncthreads();
  int base[E_];
  #pragma unroll
  for (int e = 0; e < E_; ++e) base[e] = cnt[tid][e];
  for (int j = 0; j < PT; ++j) {
    int e = e_loc[j];
    int p = base[e]++;
    int s = tid*PT + j;
    if (p < CAP_) {
      pos_arr[(size_t)b*S_ + s] = p;
      slot_src[((size_t)e*B_ + b)*CAP_ + p] = s >> 1;  // token t
    } else {
      pos_arr[(size_t)b*S_ + s] = -1;
    }
  }
}

// ---------------- Transpose + fp32->bf16: in [R][Cc] -> out [Cc][R], per expert ----------------
__global__ void transpose_conv_kernel(const float* __restrict__ in, unsigned short* __restrict__ out,
                                      int R, int Cc)
{
  __shared__ float tile[32][33];
  const int e = blockIdx.z;
  const float* ine = in + (size_t)e * R * Cc;
  unsigned short* oute = out + (size_t)e * R * Cc;
  const int c0 = blockIdx.x * 32, r0 = blockIdx.y * 32;
  const int tx = threadIdx.x & 7, ty = threadIdx.x >> 3;  // 8 x 32
  float4 v = *(const float4*)(ine + (size_t)(r0 + ty) * Cc + c0 + tx*4);
  tile[ty][tx*4+0] = v.x; tile[ty][tx*4+1] = v.y;
  tile[ty][tx*4+2] = v.z; tile[ty][tx*4+3] = v.w;
  __syncthreads();
  ushort4 o;
  o.x = f2bf(tile[tx*4+0][ty]);
  o.y = f2bf(tile[tx*4+1][ty]);
  o.z = f2bf(tile[tx*4+2][ty]);
  o.w = f2bf(tile[tx*4+3][ty]);
  *(ushort4*)(oute + (size_t)(c0 + ty) * R + r0 + tx*4) = o;
}

// ---------------- Dispatch: gather x rows into [nexp][B*CAP][C] bf16 ----------------
__global__ void dispatch_kernel(const float* __restrict__ x, const int* __restrict__ slot_src,
                                const int* __restrict__ counts, unsigned short* __restrict__ Xd,
                                int e_base, int nexp)
{
  int row = (int)((blockIdx.x * blockDim.x + threadIdx.x) >> 6);
  int lane = threadIdx.x & 63;
  int total = nexp * B_ * CAP_;
  if (row >= total) return;
  int el = row / (B_*CAP_);
  int rem = row - el*(B_*CAP_);
  int b = rem / CAP_, slot = rem - b*CAP_;
  int eg = e_base + el;
  int cnt = counts[eg*B_ + b]; if (cnt > CAP_) cnt = CAP_;
  unsigned short* orow = Xd + (size_t)row * C_;
  if (slot < cnt) {
    int t = slot_src[((size_t)eg*B_ + b)*CAP_ + slot];
    const float4* xr = (const float4*)(x + ((size_t)b*T_ + t)*C_);
    #pragma unroll
    for (int i = 0; i < C_/256; ++i) {
      float4 v = xr[i*64 + lane];
      ushort4 o;
      o.x = f2bf(v.x); o.y = f2bf(v.y); o.z = f2bf(v.z); o.w = f2bf(v.w);
      ((ushort4*)orow)[i*64 + lane] = o;
    }
  } else {
    ushort4 z; z.x = z.y = z.z = z.w = 0;
    #pragma unroll
    for (int i = 0; i < C_/256; ++i) ((ushort4*)orow)[i*64 + lane] = z;
  }
}

// ---------------- GEMM: A [e][M][K] bf16  x  BT [e][N][K] bf16  (+bias, opt relu) -> Out [e][M][N] bf16
template<int RELU>
__global__ __launch_bounds__(256, 2) void gemm_bt_kernel(
    const unsigned short* __restrict__ A,
    const unsigned short* __restrict__ BT,
    const float* __restrict__ bias,      // [e][N]
    unsigned short* __restrict__ Out,
    int M, int N, int K)
{
  __shared__ __align__(16) unsigned short ldsA[128*32];
  __shared__ __align__(16) unsigned short ldsB[128*32];
  const int e = blockIdx.z;
  const unsigned short* Ae = A + (size_t)e * M * K;
  const unsigned short* Be = BT + (size_t)e * N * K;
  const float* be = bias + (size_t)e * N;
  unsigned short* Oe = Out + (size_t)e * M * N;
  const int m0 = blockIdx.y * 128, n0 = blockIdx.x * 128;
  const int tid = threadIdx.x, lane = tid & 63, w = tid >> 6;
  const int wr = w >> 1, wc = w & 1;

  floatx4 acc[4][4];
  #pragma unroll
  for (int i = 0; i < 4; ++i)
    #pragma unroll
    for (int j = 0; j < 4; ++j) acc[i][j] = (floatx4){0.f, 0.f, 0.f, 0.f};

  // staging: 512 16B-chunks per tile; thread handles chunks tid and tid+256
  const int c0 = tid, c1 = tid + 256;
  const int ar0 = c0 >> 2, ap0 = (c0 & 3) * 8;
  const int ar1 = c1 >> 2, ap1 = (c1 & 3) * 8;
  const unsigned short* agp0 = Ae + (size_t)(m0 + ar0)*K + ap0;
  const unsigned short* agp1 = Ae + (size_t)(m0 + ar1)*K + ap1;
  const unsigned short* bgp0 = Be + (size_t)(n0 + ar0)*K + ap0;
  const unsigned short* bgp1 = Be + (size_t)(n0 + ar1)*K + ap1;

  short8 sA0 = *(const short8*)(agp0);
  short8 sA1 = *(const short8*)(agp1);
  short8 sB0 = *(const short8*)(bgp0);
  short8 sB1 = *(const short8*)(bgp1);

  short8* wAp = (short8*)ldsA;
  short8* wBp = (short8*)ldsB;

  const int fRow = lane & 15, fK = (lane >> 4) * 8;
  const unsigned short* raBase = ldsA + (size_t)(wr*64 + fRow)*32 + fK;
  const unsigned short* rbBase = ldsB + (size_t)(wc*64 + fRow)*32 + fK;

  const int nk = K / 32;
  for (int kt = 0; kt < nk; ++kt) {
    __syncthreads();
    wAp[c0] = sA0; wAp[c1] = sA1;
    wBp[c0] = sB0; wBp[c1] = sB1;
    __syncthreads();
    if (kt + 1 < nk) {
      const int koff = (kt + 1) * 32;
      sA0 = *(const short8*)(agp0 + koff);
      sA1 = *(const short8*)(agp1 + koff);
      sB0 = *(const short8*)(bgp0 + koff);
      sB1 = *(const short8*)(bgp1 + koff);
    }
    short8 af[4], bf[4];
    #pragma unroll
    for (int m = 0; m < 4; ++m) af[m] = *(const short8*)(raBase + m*16*32);
    #pragma unroll
    for (int n = 0; n < 4; ++n) bf[n] = *(const short8*)(rbBase + n*16*32);
    #pragma unroll
    for (int m = 0; m < 4; ++m)
      #pragma unroll
      for (int n = 0; n < 4; ++n)
        acc[m][n] = __builtin_amdgcn_mfma_f32_16x16x32_bf16(af[m], bf[n], acc[m][n], 0, 0, 0);
  }

  // epilogue: C/D layout col = lane&15, row = (lane>>4)*4 + reg
  const int col = lane & 15, rbase = (lane >> 4) * 4;
  #pragma unroll
  for (int m = 0; m < 4; ++m) {
    const int gr0 = m0 + wr*64 + m*16 + rbase;
    #pragma unroll
    for (int n = 0; n < 4; ++n) {
      const int gc = n0 + wc*64 + n*16 + col;
      const float bv = be[gc];
      #pragma unroll
      for (int r = 0; r < 4; ++r) {
        float v = acc[m][n][r] + bv;
        if (RELU) v = fmaxf(v, 0.f);
        Oe[(size_t)(gr0 + r)*N + gc] = f2bf(v);
      }
    }
  }
}

// ---------------- Combine: out[b,t] = sum_k p_k * y[e_k, b, pos_k] ----------------
__global__ void combine_kernel(const unsigned short* __restrict__ Y, // [E][B*CAP][C] bf16
                               const int* __restrict__ topk_e, const float* __restrict__ topk_p,
                               const int* __restrict__ pos_arr, float* __restrict__ out)
{
  int token = (int)((blockIdx.x * blockDim.x + threadIdx.x) >> 6);
  int lane = threadIdx.x & 63;
  if (token >= NTOK) return;
  int b = token / T_, t = token - b*T_;
  int s0 = b*S_ + t*2;
  float acc[16];
  #pragma unroll
  for (int i = 0; i < 16; ++i) acc[i] = 0.f;
  #pragma unroll
  for (int k = 0; k < 2; ++k) {
    int pos = pos_arr[s0 + k];
    if (pos < 0) continue;
    int e = topk_e[s0 + k];
    float p = topk_p[s0 + k];
    const unsigned short* yr = Y + (((size_t)e*B_ + b)*CAP_ + pos) * C_;
    #pragma unroll
    for (int i = 0; i < 4; ++i) {
      ushort4 v = ((const ushort4*)yr)[i*64 + lane];
      acc[i*4+0] += p * bf2f(v.x);
      acc[i*4+1] += p * bf2f(v.y);
      acc[i*4+2] += p * bf2f(v.z);
      acc[i*4+3] += p * bf2f(v.w);
    }
  }
  float4* orow = (float4*)(out + (size_t)token * C_);
  #pragma unroll
  for (int i = 0; i < 4; ++i) {
    float4 o;
    o.x = acc[i*4+0]; o.y = acc[i*4+1]; o.z = acc[i*4+2]; o.w = acc[i*4+3];
    orow[i*64 + lane] = o;
  }
}

extern "C" void kernel_launch(void* const* d_in, const int* in_sizes, int n_in,
                              void* d_out, int out_size, void* d_ws, size_t ws_size,
                              hipStream_t stream)
{
  const float* x  = (const float*)d_in[0];
  const float* Wg = (const float*)d_in[1];
  const float* bg = (const float*)d_in[2];
  const float* W1 = (const float*)d_in[3];
  const float* b1 = (const float*)d_in[4];
  const float* W2 = (const float*)d_in[5];
  const float* b2 = (const float*)d_in[6];
  float* out = (float*)d_out;

  char* ws = (char*)d_ws;
  size_t off = 0;
  auto alloc = [&](size_t bytes) -> char* {
    char* p = ws + off;
    off = (off + bytes + 255) & ~(size_t)255;
    return p;
  };
  int*   topk_e  = (int*)  alloc((size_t)NTOK * K_ * 4);
  float* topk_p  = (float*)alloc((size_t)NTOK * K_ * 4);
  int*   pos_arr = (int*)  alloc((size_t)B_ * S_ * 4);
  int*   slot_src= (int*)  alloc((size_t)E_ * B_ * CAP_ * 4);
  int*   counts  = (int*)  alloc((size_t)E_ * B_ * 4);
  unsigned short* Ybuf = (unsigned short*)alloc((size_t)E_ * ROWS_PER_E * C_ * 2);
  size_t fixed = off;
  const size_t perE = (size_t)C_ * DFF_ * 2      // W^T
                    + (size_t)ROWS_PER_E * C_ * 2  // Xdisp
                    + (size_t)ROWS_PER_E * DFF_ * 2 // H
                    + 3 * 256;
  int k = 8;
  while (k > 1 && fixed + (size_t)k * perE > ws_size) k >>= 1;
  unsigned short* Wt = (unsigned short*)alloc((size_t)k * C_ * DFF_ * 2);
  unsigned short* Xd = (unsigned short*)alloc((size_t)k * ROWS_PER_E * C_ * 2);
  unsigned short* Hb = (unsigned short*)alloc((size_t)k * ROWS_PER_E * DFF_ * 2);

  router_kernel<<<NTOK/4, 256, 0, stream>>>(x, Wg, bg, topk_e, topk_p);
  scan_kernel<<<B_, 256, 0, stream>>>(topk_e, pos_arr, slot_src, counts);

  for (int eb = 0; eb < E_; eb += k) {
    // W1 [C][DFF] -> Wt [DFF][C] bf16
    transpose_conv_kernel<<<dim3(DFF_/32, C_/32, k), 256, 0, stream>>>(
        W1 + (size_t)eb * C_ * DFF_, Wt, C_, DFF_);
    dispatch_kernel<<<(k * ROWS_PER_E) / 4, 256, 0, stream>>>(x, slot_src, counts, Xd, eb, k);
    // H = relu(Xd @ W1 + b1)
    gemm_bt_kernel<1><<<dim3(DFF_/128, ROWS_PER_E/128, k), 256, 0, stream>>>(
        Xd, Wt, b1 + (size_t)eb * DFF_, Hb, ROWS_PER_E, DFF_, C_);
    // W2 [DFF][C] -> Wt [C][DFF] bf16 (reuses Wt; stream-ordered after GEMM1)
    transpose_conv_kernel<<<dim3(C_/32, DFF_/32, k), 256, 0, stream>>>(
        W2 + (size_t)eb * DFF_ * C_, Wt, DFF_, C_);
    // Y = H @ W2 + b2
    gemm_bt_kernel<0><<<dim3(C_/128, ROWS_PER_E/128, k), 256, 0, stream>>>(
        Hb, Wt, b2 + (size_t)eb * C_, Ybuf + (size_t)eb * ROWS_PER_E * C_, ROWS_PER_E, C_, DFF_);
  }

  combine_kernel<<<NTOK/4, 256, 0, stream>>>(Ybuf, topk_e, topk_p, pos_arr, out);
}

// Round 2
// 645.160 us; speedup vs baseline: 1.0108x; 1.0108x over previous
//
#include <hip/hip_runtime.h>
#include <stdint.h>

#define B_ 8
#define T_ 2048
#define C_ 1024
#define E_ 8
#define K_ 2
#define CAP_ 320
#define DFF_ 4096
#define S_ (T_*K_)          // 4096 assignments per batch row
#define NTOK (B_*T_)        // 16384 tokens
#define ROWS_PER_E (B_*CAP_) // 2560

typedef __attribute__((ext_vector_type(8))) short short8;
typedef __attribute__((ext_vector_type(4))) float floatx4;

__device__ __forceinline__ unsigned short f2bf(float f) {
  union { float f; unsigned u; } v; v.f = f;
  unsigned r = v.u + 0x7fffu + ((v.u >> 16) & 1u);
  return (unsigned short)(r >> 16);
}
__device__ __forceinline__ float bf2f(unsigned short h) {
  union { unsigned u; float f; } v; v.u = ((unsigned)h) << 16;
  return v.f;
}

// async global->LDS, 16B per lane; LDS dest is wave-uniform base + lane*16
#define GLOAD16(g, l) __builtin_amdgcn_global_load_lds( \
    (const __attribute__((address_space(1))) void*)(g), \
    (__attribute__((address_space(3))) void*)(l), 16, 0, 0)

// ---------------- Router: fp64 logits, softmax, top-2 ----------------
__global__ void router_kernel(const float* __restrict__ x, const float* __restrict__ Wg,
                              const float* __restrict__ bg,
                              int* __restrict__ topk_e, float* __restrict__ topk_p)
{
  int token = (int)((blockIdx.x * blockDim.x + threadIdx.x) >> 6);
  int lane = threadIdx.x & 63;
  if (token >= NTOK) return;
  const float* xr = x + (size_t)token * C_;
  double acc[E_];
  #pragma unroll
  for (int e = 0; e < E_; ++e) acc[e] = 0.0;
  for (int c = lane; c < C_; c += 64) {
    double xv = (double)xr[c];
    const float4* w4 = (const float4*)(Wg + (size_t)c * E_);
    float4 wa = w4[0], wb = w4[1];
    acc[0] += xv * (double)wa.x; acc[1] += xv * (double)wa.y;
    acc[2] += xv * (double)wa.z; acc[3] += xv * (double)wa.w;
    acc[4] += xv * (double)wb.x; acc[5] += xv * (double)wb.y;
    acc[6] += xv * (double)wb.z; acc[7] += xv * (double)wb.w;
  }
  #pragma unroll
  for (int off = 32; off; off >>= 1) {
    #pragma unroll
    for (int e = 0; e < E_; ++e) acc[e] += __shfl_down(acc[e], off, 64);
  }
  if (lane == 0) {
    double lg[E_];
    double mx = -1e300;
    #pragma unroll
    for (int e = 0; e < E_; ++e) { lg[e] = acc[e] + (double)bg[e]; mx = fmax(mx, lg[e]); }
    double se = 0.0, pr[E_];
    #pragma unroll
    for (int e = 0; e < E_; ++e) { pr[e] = exp(lg[e] - mx); se += pr[e]; }
    #pragma unroll
    for (int e = 0; e < E_; ++e) pr[e] /= se;
    int e0 = 0;
    #pragma unroll
    for (int e = 1; e < E_; ++e) if (pr[e] > pr[e0]) e0 = e;
    int e1 = -1;
    #pragma unroll
    for (int e = 0; e < E_; ++e) {
      if (e == e0) continue;
      if (e1 < 0 || pr[e] > pr[e1]) e1 = e;
    }
    topk_e[token*2+0] = e0; topk_p[token*2+0] = (float)pr[e0];
    topk_e[token*2+1] = e1; topk_p[token*2+1] = (float)pr[e1];
  }
}

// ---------------- Scan: per-(b,e) positions, capacity, slot map ----------------
__global__ void scan_kernel(const int* __restrict__ topk_e,
                            int* __restrict__ pos_arr,   // [B_*S_], -1 if dropped
                            int* __restrict__ slot_src,  // [E_*B_*CAP_] -> src token t
                            int* __restrict__ counts)    // [E_*B_]
{
  const int b = blockIdx.x;
  const int tid = threadIdx.x;
  const int PT = S_ / 256; // 16
  __shared__ int cnt[256][E_];
  int e_loc[16];
  int local[E_];
  #pragma unroll
  for (int e = 0; e < E_; ++e) local[e] = 0;
  const int* te = topk_e + (size_t)b * S_;
  for (int j = 0; j < PT; ++j) {
    int e = te[tid*PT + j];
    e_loc[j] = e;
    local[e]++;
  }
  #pragma unroll
  for (int e = 0; e < E_; ++e) cnt[tid][e] = local[e];
  __syncthreads();
  if (tid < E_) {
    int run = 0;
    for (int i = 0; i < 256; ++i) { int v = cnt[i][tid]; cnt[i][tid] = run; run += v; }
    counts[tid*B_ + b] = run;   // counts[e][b]
  }
  __syncthreads();
  int base[E_];
  #pragma unroll
  for (int e = 0; e < E_; ++e) base[e] = cnt[tid][e];
  for (int j = 0; j < PT; ++j) {
    int e = e_loc[j];
    int p = base[e]++;
    int s = tid*PT + j;
    if (p < CAP_) {
      pos_arr[(size_t)b*S_ + s] = p;
      slot_src[((size_t)e*B_ + b)*CAP_ + p] = s >> 1;  // token t
    } else {
      pos_arr[(size_t)b*S_ + s] = -1;
    }
  }
}

// ---------------- Transpose + fp32->bf16: in [R][Cc] -> out [Cc][R], per expert ----------------
__global__ void transpose_conv_kernel(const float* __restrict__ in, unsigned short* __restrict__ out,
                                      int R, int Cc)
{
  __shared__ float tile[32][33];
  const int e = blockIdx.z;
  const float* ine = in + (size_t)e * R * Cc;
  unsigned short* oute = out + (size_t)e * R * Cc;
  const int c0 = blockIdx.x * 32, r0 = blockIdx.y * 32;
  const int tx = threadIdx.x & 7, ty = threadIdx.x >> 3;  // 8 x 32
  float4 v = *(const float4*)(ine + (size_t)(r0 + ty) * Cc + c0 + tx*4);
  tile[ty][tx*4+0] = v.x; tile[ty][tx*4+1] = v.y;
  tile[ty][tx*4+2] = v.z; tile[ty][tx*4+3] = v.w;
  __syncthreads();
  ushort4 o;
  o.x = f2bf(tile[tx*4+0][ty]);
  o.y = f2bf(tile[tx*4+1][ty]);
  o.z = f2bf(tile[tx*4+2][ty]);
  o.w = f2bf(tile[tx*4+3][ty]);
  *(ushort4*)(oute + (size_t)(c0 + ty) * R + r0 + tx*4) = o;
}

// ---------------- Dispatch: gather x rows into [nexp][B*CAP][C] bf16 ----------------
__global__ void dispatch_kernel(const float* __restrict__ x, const int* __restrict__ slot_src,
                                const int* __restrict__ counts, unsigned short* __restrict__ Xd,
                                int e_base, int nexp)
{
  int row = (int)((blockIdx.x * blockDim.x + threadIdx.x) >> 6);
  int lane = threadIdx.x & 63;
  int total = nexp * B_ * CAP_;
  if (row >= total) return;
  int el = row / (B_*CAP_);
  int rem = row - el*(B_*CAP_);
  int b = rem / CAP_, slot = rem - b*CAP_;
  int eg = e_base + el;
  int cnt = counts[eg*B_ + b]; if (cnt > CAP_) cnt = CAP_;
  unsigned short* orow = Xd + (size_t)row * C_;
  if (slot < cnt) {
    int t = slot_src[((size_t)eg*B_ + b)*CAP_ + slot];
    const float4* xr = (const float4*)(x + ((size_t)b*T_ + t)*C_);
    #pragma unroll
    for (int i = 0; i < C_/256; ++i) {
      float4 v = xr[i*64 + lane];
      ushort4 o;
      o.x = f2bf(v.x); o.y = f2bf(v.y); o.z = f2bf(v.z); o.w = f2bf(v.w);
      ((ushort4*)orow)[i*64 + lane] = o;
    }
  } else {
    ushort4 z; z.x = z.y = z.z = z.w = 0;
    #pragma unroll
    for (int i = 0; i < C_/256; ++i) ((ushort4*)orow)[i*64 + lane] = z;
  }
}

// ---------------- GEMM (m97 structure): A [e][M][K] bf16 x BT [e][N][K] bf16 (+bias, opt relu) -> Out [e][M][N] bf16
// 128x128 tile, BK=32, 4 waves, global_load_lds width-16 staging (linear LDS),
// 2 barriers per K-step; next-tile loads in flight under the MFMAs.
template<int RELU>
__global__ __launch_bounds__(256, 3) void gemm_bt_kernel(
    const unsigned short* __restrict__ A,
    const unsigned short* __restrict__ BT,
    const float* __restrict__ bias,      // [e][N]
    unsigned short* __restrict__ Out,
    int M, int N, int K)
{
  __shared__ __align__(16) unsigned short ldsA[128*32];
  __shared__ __align__(16) unsigned short ldsB[128*32];
  const int e = blockIdx.z;
  const unsigned short* Ae = A + (size_t)e * M * K;
  const unsigned short* Be = BT + (size_t)e * N * K;
  const float* be = bias + (size_t)e * N;
  unsigned short* Oe = Out + (size_t)e * M * N;
  const int m0 = blockIdx.y * 128, n0 = blockIdx.x * 128;
  const int tid = threadIdx.x, lane = tid & 63, w = tid >> 6;
  const int wr = w >> 1, wc = w & 1;

  floatx4 acc[4][4];
  #pragma unroll
  for (int i = 0; i < 4; ++i)
    #pragma unroll
    for (int j = 0; j < 4; ++j) acc[i][j] = (floatx4){0.f, 0.f, 0.f, 0.f};

  // tile = 128 rows x 32 K of bf16 = 8192 B = 512 chunks of 16B.
  // chunk c -> row c>>2, kpos (c&3)*8. Wave w, call q covers chunks q*256 + w*64 + lane.
  const int cA0 = tid;            // q=0 chunk for this thread
  const int cA1 = 256 + tid;      // q=1 chunk
  const int r0c = cA0 >> 2, p0c = (cA0 & 3) * 8;
  const int r1c = cA1 >> 2, p1c = (cA1 & 3) * 8;
  const unsigned short* ga0 = Ae + (size_t)(m0 + r0c)*K + p0c;
  const unsigned short* ga1 = Ae + (size_t)(m0 + r1c)*K + p1c;
  const unsigned short* gb0 = Be + (size_t)(n0 + r0c)*K + p0c;
  const unsigned short* gb1 = Be + (size_t)(n0 + r1c)*K + p1c;
  // wave-uniform LDS bases (elements): call q base = (q*256 + w*64)*8 shorts
  unsigned short* laq0 = ldsA + (size_t)w * 512;
  unsigned short* laq1 = ldsA + 2048 + (size_t)w * 512;
  unsigned short* lbq0 = ldsB + (size_t)w * 512;
  unsigned short* lbq1 = ldsB + 2048 + (size_t)w * 512;

  const int fRow = lane & 15, fK = (lane >> 4) * 8;
  const unsigned short* raBase = ldsA + (size_t)(wr*64 + fRow)*32 + fK;
  const unsigned short* rbBase = ldsB + (size_t)(wc*64 + fRow)*32 + fK;

  const int nk = K / 32;
  // prologue: stage tile 0
  GLOAD16(ga0, laq0);
  GLOAD16(ga1, laq1);
  GLOAD16(gb0, lbq0);
  GLOAD16(gb1, lbq1);
  __syncthreads();   // vmcnt(0) drain -> tile 0 visible to all waves

  for (int kt = 0; kt < nk; ++kt) {
    short8 af[4], bf[4];
    #pragma unroll
    for (int m = 0; m < 4; ++m) af[m] = *(const short8*)(raBase + m*512);
    #pragma unroll
    for (int n = 0; n < 4; ++n) bf[n] = *(const short8*)(rbBase + n*512);
    __syncthreads();   // all waves finished reading tile kt -> safe to overwrite
    if (kt + 1 < nk) {
      const int koff = (kt + 1) * 32;
      GLOAD16(ga0 + koff, laq0);
      GLOAD16(ga1 + koff, laq1);
      GLOAD16(gb0 + koff, lbq0);
      GLOAD16(gb1 + koff, lbq1);
    }
    #pragma unroll
    for (int m = 0; m < 4; ++m)
      #pragma unroll
      for (int n = 0; n < 4; ++n)
        acc[m][n] = __builtin_amdgcn_mfma_f32_16x16x32_bf16(af[m], bf[n], acc[m][n], 0, 0, 0);
    __syncthreads();   // vmcnt(0) drain -> tile kt+1 ready
  }

  // epilogue: C/D layout col = lane&15, row = (lane>>4)*4 + reg
  const int col = lane & 15, rbase = (lane >> 4) * 4;
  #pragma unroll
  for (int m = 0; m < 4; ++m) {
    const int gr0 = m0 + wr*64 + m*16 + rbase;
    #pragma unroll
    for (int n = 0; n < 4; ++n) {
      const int gc = n0 + wc*64 + n*16 + col;
      const float bv = be[gc];
      #pragma unroll
      for (int r = 0; r < 4; ++r) {
        float v = acc[m][n][r] + bv;
        if (RELU) v = fmaxf(v, 0.f);
        Oe[(size_t)(gr0 + r)*N + gc] = f2bf(v);
      }
    }
  }
}

// ---------------- Combine: out[b,t] = sum_k p_k * y[e_k, b, pos_k] ----------------
__global__ void combine_kernel(const unsigned short* __restrict__ Y, // [E][B*CAP][C] bf16
                               const int* __restrict__ topk_e, const float* __restrict__ topk_p,
                               const int* __restrict__ pos_arr, float* __restrict__ out)
{
  int token = (int)((blockIdx.x * blockDim.x + threadIdx.x) >> 6);
  int lane = threadIdx.x & 63;
  if (token >= NTOK) return;
  int b = token / T_, t = token - b*T_;
  int s0 = b*S_ + t*2;
  float acc[16];
  #pragma unroll
  for (int i = 0; i < 16; ++i) acc[i] = 0.f;
  #pragma unroll
  for (int k = 0; k < 2; ++k) {
    int pos = pos_arr[s0 + k];
    if (pos < 0) continue;
    int e = topk_e[s0 + k];
    float p = topk_p[s0 + k];
    const unsigned short* yr = Y + (((size_t)e*B_ + b)*CAP_ + pos) * C_;
    #pragma unroll
    for (int i = 0; i < 4; ++i) {
      ushort4 v = ((const ushort4*)yr)[i*64 + lane];
      acc[i*4+0] += p * bf2f(v.x);
      acc[i*4+1] += p * bf2f(v.y);
      acc[i*4+2] += p * bf2f(v.z);
      acc[i*4+3] += p * bf2f(v.w);
    }
  }
  float4* orow = (float4*)(out + (size_t)token * C_);
  #pragma unroll
  for (int i = 0; i < 4; ++i) {
    float4 o;
    o.x = acc[i*4+0]; o.y = acc[i*4+1]; o.z = acc[i*4+2]; o.w = acc[i*4+3];
    orow[i*64 + lane] = o;
  }
}

extern "C" void kernel_launch(void* const* d_in, const int* in_sizes, int n_in,
                              void* d_out, int out_size, void* d_ws, size_t ws_size,
                              hipStream_t stream)
{
  const float* x  = (const float*)d_in[0];
  const float* Wg = (const float*)d_in[1];
  const float* bg = (const float*)d_in[2];
  const float* W1 = (const float*)d_in[3];
  const float* b1 = (const float*)d_in[4];
  const float* W2 = (const float*)d_in[5];
  const float* b2 = (const float*)d_in[6];
  float* out = (float*)d_out;

  char* ws = (char*)d_ws;
  size_t off = 0;
  auto alloc = [&](size_t bytes) -> char* {
    char* p = ws + off;
    off = (off + bytes + 255) & ~(size_t)255;
    return p;
  };
  int*   topk_e  = (int*)  alloc((size_t)NTOK * K_ * 4);
  float* topk_p  = (float*)alloc((size_t)NTOK * K_ * 4);
  int*   pos_arr = (int*)  alloc((size_t)B_ * S_ * 4);
  int*   slot_src= (int*)  alloc((size_t)E_ * B_ * CAP_ * 4);
  int*   counts  = (int*)  alloc((size_t)E_ * B_ * 4);
  unsigned short* Ybuf = (unsigned short*)alloc((size_t)E_ * ROWS_PER_E * C_ * 2);
  size_t fixed = off;
  const size_t perE = (size_t)C_ * DFF_ * 2      // W^T
                    + (size_t)ROWS_PER_E * C_ * 2  // Xdisp
                    + (size_t)ROWS_PER_E * DFF_ * 2 // H
                    + 3 * 256;
  int k = 8;
  while (k > 1 && fixed + (size_t)k * perE > ws_size) k >>= 1;
  unsigned short* Wt = (unsigned short*)alloc((size_t)k * C_ * DFF_ * 2);
  unsigned short* Xd = (unsigned short*)alloc((size_t)k * ROWS_PER_E * C_ * 2);
  unsigned short* Hb = (unsigned short*)alloc((size_t)k * ROWS_PER_E * DFF_ * 2);

  router_kernel<<<NTOK/4, 256, 0, stream>>>(x, Wg, bg, topk_e, topk_p);
  scan_kernel<<<B_, 256, 0, stream>>>(topk_e, pos_arr, slot_src, counts);

  for (int eb = 0; eb < E_; eb += k) {
    // W1 [C][DFF] -> Wt [DFF][C] bf16
    transpose_conv_kernel<<<dim3(DFF_/32, C_/32, k), 256, 0, stream>>>(
        W1 + (size_t)eb * C_ * DFF_, Wt, C_, DFF_);
    dispatch_kernel<<<(k * ROWS_PER_E) / 4, 256, 0, stream>>>(x, slot_src, counts, Xd, eb, k);
    // H = relu(Xd @ W1 + b1)
    gemm_bt_kernel<1><<<dim3(DFF_/128, ROWS_PER_E/128, k), 256, 0, stream>>>(
        Xd, Wt, b1 + (size_t)eb * DFF_, Hb, ROWS_PER_E, DFF_, C_);
    // W2 [DFF][C] -> Wt [C][DFF] bf16 (reuses Wt; stream-ordered after GEMM1)
    transpose_conv_kernel<<<dim3(C_/32, DFF_/32, k), 256, 0, stream>>>(
        W2 + (size_t)eb * DFF_ * C_, Wt, DFF_, C_);
    // Y = H @ W2 + b2
    gemm_bt_kernel<0><<<dim3(C_/128, ROWS_PER_E/128, k), 256, 0, stream>>>(
        Hb, Wt, b2 + (size_t)eb * C_, Ybuf + (size_t)eb * ROWS_PER_E * C_, ROWS_PER_E, C_, DFF_);
  }

  combine_kernel<<<NTOK/4, 256, 0, stream>>>(Ybuf, topk_e, topk_p, pos_arr, out);
}

// Round 3
// 611.668 us; speedup vs baseline: 1.0662x; 1.0548x over previous
//
#include <hip/hip_runtime.h>
#include <stdint.h>

#define B_ 8
#define T_ 2048
#define C_ 1024
#define E_ 8
#define K_ 2
#define CAP_ 320
#define DFF_ 4096
#define S_ (T_*K_)          // 4096 assignments per batch row
#define NTOK (B_*T_)        // 16384 tokens
#define ROWS_PER_E (B_*CAP_) // 2560

typedef __attribute__((ext_vector_type(8))) short short8;
typedef __attribute__((ext_vector_type(4))) float floatx4;

__device__ __forceinline__ unsigned short f2bf(float f) {
  union { float f; unsigned u; } v; v.f = f;
  unsigned r = v.u + 0x7fffu + ((v.u >> 16) & 1u);
  return (unsigned short)(r >> 16);
}
__device__ __forceinline__ float bf2f(unsigned short h) {
  union { unsigned u; float f; } v; v.u = ((unsigned)h) << 16;
  return v.f;
}

// async global->LDS, 16B per lane; LDS dest is wave-uniform base + lane*16
#define GLOAD16(g, l) __builtin_amdgcn_global_load_lds( \
    (const __attribute__((address_space(1))) void*)(g), \
    (__attribute__((address_space(3))) void*)(l), 16, 0, 0)

// ---------------- Router: fp64 logits, softmax, top-2 ----------------
__global__ void router_kernel(const float* __restrict__ x, const float* __restrict__ Wg,
                              const float* __restrict__ bg,
                              int* __restrict__ topk_e, float* __restrict__ topk_p)
{
  int token = (int)((blockIdx.x * blockDim.x + threadIdx.x) >> 6);
  int lane = threadIdx.x & 63;
  if (token >= NTOK) return;
  const float* xr = x + (size_t)token * C_;
  double acc[E_];
  #pragma unroll
  for (int e = 0; e < E_; ++e) acc[e] = 0.0;
  for (int c = lane; c < C_; c += 64) {
    double xv = (double)xr[c];
    const float4* w4 = (const float4*)(Wg + (size_t)c * E_);
    float4 wa = w4[0], wb = w4[1];
    acc[0] += xv * (double)wa.x; acc[1] += xv * (double)wa.y;
    acc[2] += xv * (double)wa.z; acc[3] += xv * (double)wa.w;
    acc[4] += xv * (double)wb.x; acc[5] += xv * (double)wb.y;
    acc[6] += xv * (double)wb.z; acc[7] += xv * (double)wb.w;
  }
  #pragma unroll
  for (int off = 32; off; off >>= 1) {
    #pragma unroll
    for (int e = 0; e < E_; ++e) acc[e] += __shfl_down(acc[e], off, 64);
  }
  if (lane == 0) {
    double lg[E_];
    double mx = -1e300;
    #pragma unroll
    for (int e = 0; e < E_; ++e) { lg[e] = acc[e] + (double)bg[e]; mx = fmax(mx, lg[e]); }
    double se = 0.0, pr[E_];
    #pragma unroll
    for (int e = 0; e < E_; ++e) { pr[e] = exp(lg[e] - mx); se += pr[e]; }
    #pragma unroll
    for (int e = 0; e < E_; ++e) pr[e] /= se;
    int e0 = 0;
    #pragma unroll
    for (int e = 1; e < E_; ++e) if (pr[e] > pr[e0]) e0 = e;
    int e1 = -1;
    #pragma unroll
    for (int e = 0; e < E_; ++e) {
      if (e == e0) continue;
      if (e1 < 0 || pr[e] > pr[e1]) e1 = e;
    }
    topk_e[token*2+0] = e0; topk_p[token*2+0] = (float)pr[e0];
    topk_e[token*2+1] = e1; topk_p[token*2+1] = (float)pr[e1];
  }
}

// ---------------- Scan: per-(b,e) positions, capacity, slot map ----------------
__global__ void scan_kernel(const int* __restrict__ topk_e,
                            int* __restrict__ pos_arr,   // [B_*S_], -1 if dropped
                            int* __restrict__ slot_src,  // [E_*B_*CAP_] -> src token t
                            int* __restrict__ counts)    // [E_*B_]
{
  const int b = blockIdx.x;
  const int tid = threadIdx.x;
  const int PT = S_ / 256; // 16
  __shared__ int cnt[256][E_];
  int e_loc[16];
  int local[E_];
  #pragma unroll
  for (int e = 0; e < E_; ++e) local[e] = 0;
  const int* te = topk_e + (size_t)b * S_;
  for (int j = 0; j < PT; ++j) {
    int e = te[tid*PT + j];
    e_loc[j] = e;
    local[e]++;
  }
  #pragma unroll
  for (int e = 0; e < E_; ++e) cnt[tid][e] = local[e];
  __syncthreads();
  if (tid < E_) {
    int run = 0;
    for (int i = 0; i < 256; ++i) { int v = cnt[i][tid]; cnt[i][tid] = run; run += v; }
    counts[tid*B_ + b] = run;   // counts[e][b]
  }
  __syncthreads();
  int base[E_];
  #pragma unroll
  for (int e = 0; e < E_; ++e) base[e] = cnt[tid][e];
  for (int j = 0; j < PT; ++j) {
    int e = e_loc[j];
    int p = base[e]++;
    int s = tid*PT + j;
    if (p < CAP_) {
      pos_arr[(size_t)b*S_ + s] = p;
      slot_src[((size_t)e*B_ + b)*CAP_ + p] = s >> 1;  // token t
    } else {
      pos_arr[(size_t)b*S_ + s] = -1;
    }
  }
}

// ---------------- Transpose + fp32->bf16: in [R][Cc] -> out [Cc][R], per expert ----------------
__global__ void transpose_conv_kernel(const float* __restrict__ in, unsigned short* __restrict__ out,
                                      int R, int Cc)
{
  __shared__ float tile[32][33];
  const int e = blockIdx.z;
  const float* ine = in + (size_t)e * R * Cc;
  unsigned short* oute = out + (size_t)e * R * Cc;
  const int c0 = blockIdx.x * 32, r0 = blockIdx.y * 32;
  const int tx = threadIdx.x & 7, ty = threadIdx.x >> 3;  // 8 x 32
  float4 v = *(const float4*)(ine + (size_t)(r0 + ty) * Cc + c0 + tx*4);
  tile[ty][tx*4+0] = v.x; tile[ty][tx*4+1] = v.y;
  tile[ty][tx*4+2] = v.z; tile[ty][tx*4+3] = v.w;
  __syncthreads();
  ushort4 o;
  o.x = f2bf(tile[tx*4+0][ty]);
  o.y = f2bf(tile[tx*4+1][ty]);
  o.z = f2bf(tile[tx*4+2][ty]);
  o.w = f2bf(tile[tx*4+3][ty]);
  *(ushort4*)(oute + (size_t)(c0 + ty) * R + r0 + tx*4) = o;
}

// ---------------- Dispatch: gather x rows into [nexp][B*CAP][C] bf16 ----------------
__global__ void dispatch_kernel(const float* __restrict__ x, const int* __restrict__ slot_src,
                                const int* __restrict__ counts, unsigned short* __restrict__ Xd,
                                int e_base, int nexp)
{
  int row = (int)((blockIdx.x * blockDim.x + threadIdx.x) >> 6);
  int lane = threadIdx.x & 63;
  int total = nexp * B_ * CAP_;
  if (row >= total) return;
  int el = row / (B_*CAP_);
  int rem = row - el*(B_*CAP_);
  int b = rem / CAP_, slot = rem - b*CAP_;
  int eg = e_base + el;
  int cnt = counts[eg*B_ + b]; if (cnt > CAP_) cnt = CAP_;
  unsigned short* orow = Xd + (size_t)row * C_;
  if (slot < cnt) {
    int t = slot_src[((size_t)eg*B_ + b)*CAP_ + slot];
    const float4* xr = (const float4*)(x + ((size_t)b*T_ + t)*C_);
    #pragma unroll
    for (int i = 0; i < C_/256; ++i) {
      float4 v = xr[i*64 + lane];
      ushort4 o;
      o.x = f2bf(v.x); o.y = f2bf(v.y); o.z = f2bf(v.z); o.w = f2bf(v.w);
      ((ushort4*)orow)[i*64 + lane] = o;
    }
  } else {
    ushort4 z; z.x = z.y = z.z = z.w = 0;
    #pragma unroll
    for (int i = 0; i < C_/256; ++i) ((ushort4*)orow)[i*64 + lane] = z;
  }
}

// ---------------- GEMM 256x256, BK=32, ring-4 LDS, counted-vmcnt deep pipeline ----------------
// A [e][M][K] bf16 x BT [e][N][K] bf16 (+bias, opt relu) -> Out [e][M][N] bf16
// 512 threads = 8 waves (2M x 4N), per-wave 128x64 output.
// Ring of 4 K-tile slots (32KB each: A 16KB + B 16KB), prefetch 3 tiles ahead,
// vmcnt(8) at tile boundaries (never 0 until the tail). 2 phases per tile,
// 16 MFMA each, setprio around MFMA cluster.
template<int RELU>
__global__ __launch_bounds__(512) void gemm256_kernel(
    const unsigned short* __restrict__ A,
    const unsigned short* __restrict__ BT,
    const float* __restrict__ bias,      // [e][N]
    unsigned short* __restrict__ Out,
    int M, int N, int K, int nwg)
{
  __shared__ __align__(16) unsigned short lds[4*16384]; // 128 KiB: 4 slots x (A 8192 + B 8192 shorts)
  const int NT = N >> 8, MT = M >> 8;
  const int bid = blockIdx.x;
  // bijective XCD swizzle (nwg % 8 == 0 for all launch configs here)
  const int wg = (bid & 7) * (nwg >> 3) + (bid >> 3);
  const int e  = wg / (MT*NT);
  const int r2 = wg - e*(MT*NT);
  const int mt = r2 / NT, nt = r2 - mt*NT;
  const unsigned short* Ae = A + (size_t)e * M * K;
  const unsigned short* Be = BT + (size_t)e * N * K;
  const float* be = bias + (size_t)e * N;
  unsigned short* Oe = Out + (size_t)e * M * N;
  const int m0 = mt*256, n0 = nt*256;

  const int tid = threadIdx.x, lane = tid & 63, w = tid >> 6;
  const int wr = w >> 2, wc = w & 3;   // 2 x 4 waves

  floatx4 acc[8][4];
  #pragma unroll
  for (int i = 0; i < 8; ++i)
    #pragma unroll
    for (int j = 0; j < 4; ++j) acc[i][j] = (floatx4){0.f, 0.f, 0.f, 0.f};

  // staging decode: per matrix-tile 1024 chunks of 16B; thread covers chunks tid, 512+tid
  const int c0 = tid, c1 = 512 + tid;
  const int sr0 = c0 >> 2, sq0 = (c0 & 3) * 8;
  const int sr1 = c1 >> 2, sq1 = (c1 & 3) * 8;
  const unsigned short* gA0 = Ae + (size_t)(m0 + sr0)*K + sq0;
  const unsigned short* gA1 = Ae + (size_t)(m0 + sr1)*K + sq1;
  const unsigned short* gB0 = Be + (size_t)(n0 + sr0)*K + sq0;
  const unsigned short* gB1 = Be + (size_t)(n0 + sr1)*K + sq1;
  const int ldsOff0 = w*512;          // shorts (wave-uniform), q=0 call
  const int ldsOff1 = 4096 + w*512;   // q=1 call

  // fragment read bases (per lane); rows are 64B so b128 reads are conflict-free
  const int fr = lane & 15, kq = lane >> 4;
  const int aOff = (wr*128 + fr)*32 + kq*8;          // shorts within A region
  const int bOff = 8192 + (wc*64 + fr)*32 + kq*8;    // shorts, B region at +8192

  const int nk = K >> 5;

#define STAGE_A(t, slot) do { \
    GLOAD16(gA0 + (size_t)(t)*32, lds + (slot)*16384 + ldsOff0); \
    GLOAD16(gA1 + (size_t)(t)*32, lds + (slot)*16384 + ldsOff1); } while(0)
#define STAGE_B(t, slot) do { \
    GLOAD16(gB0 + (size_t)(t)*32, lds + (slot)*16384 + 8192 + ldsOff0); \
    GLOAD16(gB1 + (size_t)(t)*32, lds + (slot)*16384 + 8192 + ldsOff1); } while(0)

  // prologue: stage tiles 0,1,2 into slots 0,1,2 (12 loads/thread)
  STAGE_A(0, 0); STAGE_B(0, 0);
  STAGE_A(1, 1); STAGE_B(1, 1);
  STAGE_A(2, 2); STAGE_B(2, 2);
  asm volatile("s_waitcnt vmcnt(8)" ::: "memory");   // tile 0 landed
  __builtin_amdgcn_s_barrier();

  for (int t = 0; t < nk; ++t) {
    const int slot = t & 3, ps = (t + 3) & 3;
    const unsigned short* sT = lds + slot*16384;
    const bool pf = (t + 3 < nk);
    short8 bfr[4], af[4];

    // ---- phase 1: B frags + A frags(mf0-3) | stage A(t+3) | MFMA quadrant 1 ----
    #pragma unroll
    for (int nf = 0; nf < 4; ++nf) bfr[nf] = *(const short8*)(sT + bOff + nf*512);
    #pragma unroll
    for (int mf = 0; mf < 4; ++mf) af[mf] = *(const short8*)(sT + aOff + mf*512);
    if (pf) STAGE_A(t+3, ps);
    __builtin_amdgcn_s_barrier();
    asm volatile("s_waitcnt lgkmcnt(0)" ::: "memory");
    __builtin_amdgcn_sched_barrier(0);
    __builtin_amdgcn_s_setprio(1);
    #pragma unroll
    for (int mf = 0; mf < 4; ++mf)
      #pragma unroll
      for (int nf = 0; nf < 4; ++nf)
        acc[mf][nf] = __builtin_amdgcn_mfma_f32_16x16x32_bf16(af[mf], bfr[nf], acc[mf][nf], 0, 0, 0);
    __builtin_amdgcn_s_setprio(0);
    __builtin_amdgcn_sched_barrier(0);
    __builtin_amdgcn_s_barrier();

    // ---- phase 2: A frags(mf4-7) | stage B(t+3) | MFMA quadrant 2 ----
    #pragma unroll
    for (int mf = 0; mf < 4; ++mf) af[mf] = *(const short8*)(sT + aOff + (mf+4)*512);
    if (pf) STAGE_B(t+3, ps);
    __builtin_amdgcn_s_barrier();
    asm volatile("s_waitcnt lgkmcnt(0)" ::: "memory");
    __builtin_amdgcn_sched_barrier(0);
    __builtin_amdgcn_s_setprio(1);
    #pragma unroll
    for (int mf = 0; mf < 4; ++mf)
      #pragma unroll
      for (int nf = 0; nf < 4; ++nf)
        acc[mf+4][nf] = __builtin_amdgcn_mfma_f32_16x16x32_bf16(af[mf], bfr[nf], acc[mf+4][nf], 0, 0, 0);
    __builtin_amdgcn_s_setprio(0);
    __builtin_amdgcn_sched_barrier(0);

    // tile boundary: publish tile t+1 (counted wait, never 0 until tail)
    if (t + 1 < nk) {
      if (t + 3 < nk)      asm volatile("s_waitcnt vmcnt(8)" ::: "memory");
      else if (t + 2 < nk) asm volatile("s_waitcnt vmcnt(4)" ::: "memory");
      else                 asm volatile("s_waitcnt vmcnt(0)" ::: "memory");
      __builtin_amdgcn_s_barrier();
    }
  }
#undef STAGE_A
#undef STAGE_B

  // epilogue: C/D layout col = lane&15, row = (lane>>4)*4 + reg
  const int col = lane & 15, rbase = (lane >> 4) * 4;
  #pragma unroll
  for (int mf = 0; mf < 8; ++mf) {
    const int gr0 = m0 + wr*128 + mf*16 + rbase;
    #pragma unroll
    for (int nf = 0; nf < 4; ++nf) {
      const int gc = n0 + wc*64 + nf*16 + col;
      const float bv = be[gc];
      #pragma unroll
      for (int r = 0; r < 4; ++r) {
        float v = acc[mf][nf][r] + bv;
        if (RELU) v = fmaxf(v, 0.f);
        Oe[(size_t)(gr0 + r)*N + gc] = f2bf(v);
      }
    }
  }
}

// ---------------- Combine: out[b,t] = sum_k p_k * y[e_k, b, pos_k] ----------------
__global__ void combine_kernel(const unsigned short* __restrict__ Y, // [E][B*CAP][C] bf16
                               const int* __restrict__ topk_e, const float* __restrict__ topk_p,
                               const int* __restrict__ pos_arr, float* __restrict__ out)
{
  int token = (int)((blockIdx.x * blockDim.x + threadIdx.x) >> 6);
  int lane = threadIdx.x & 63;
  if (token >= NTOK) return;
  int b = token / T_, t = token - b*T_;
  int s0 = b*S_ + t*2;
  float acc[16];
  #pragma unroll
  for (int i = 0; i < 16; ++i) acc[i] = 0.f;
  #pragma unroll
  for (int k = 0; k < 2; ++k) {
    int pos = pos_arr[s0 + k];
    if (pos < 0) continue;
    int e = topk_e[s0 + k];
    float p = topk_p[s0 + k];
    const unsigned short* yr = Y + (((size_t)e*B_ + b)*CAP_ + pos) * C_;
    #pragma unroll
    for (int i = 0; i < 4; ++i) {
      ushort4 v = ((const ushort4*)yr)[i*64 + lane];
      acc[i*4+0] += p * bf2f(v.x);
      acc[i*4+1] += p * bf2f(v.y);
      acc[i*4+2] += p * bf2f(v.z);
      acc[i*4+3] += p * bf2f(v.w);
    }
  }
  float4* orow = (float4*)(out + (size_t)token * C_);
  #pragma unroll
  for (int i = 0; i < 4; ++i) {
    float4 o;
    o.x = acc[i*4+0]; o.y = acc[i*4+1]; o.z = acc[i*4+2]; o.w = acc[i*4+3];
    orow[i*64 + lane] = o;
  }
}

extern "C" void kernel_launch(void* const* d_in, const int* in_sizes, int n_in,
                              void* d_out, int out_size, void* d_ws, size_t ws_size,
                              hipStream_t stream)
{
  const float* x  = (const float*)d_in[0];
  const float* Wg = (const float*)d_in[1];
  const float* bg = (const float*)d_in[2];
  const float* W1 = (const float*)d_in[3];
  const float* b1 = (const float*)d_in[4];
  const float* W2 = (const float*)d_in[5];
  const float* b2 = (const float*)d_in[6];
  float* out = (float*)d_out;

  char* ws = (char*)d_ws;
  size_t off = 0;
  auto alloc = [&](size_t bytes) -> char* {
    char* p = ws + off;
    off = (off + bytes + 255) & ~(size_t)255;
    return p;
  };
  int*   topk_e  = (int*)  alloc((size_t)NTOK * K_ * 4);
  float* topk_p  = (float*)alloc((size_t)NTOK * K_ * 4);
  int*   pos_arr = (int*)  alloc((size_t)B_ * S_ * 4);
  int*   slot_src= (int*)  alloc((size_t)E_ * B_ * CAP_ * 4);
  int*   counts  = (int*)  alloc((size_t)E_ * B_ * 4);
  unsigned short* Ybuf = (unsigned short*)alloc((size_t)E_ * ROWS_PER_E * C_ * 2);
  size_t fixed = off;
  const size_t perE = (size_t)C_ * DFF_ * 2      // W^T
                    + (size_t)ROWS_PER_E * C_ * 2  // Xdisp
                    + (size_t)ROWS_PER_E * DFF_ * 2 // H
                    + 3 * 256;
  int k = 8;
  while (k > 1 && fixed + (size_t)k * perE > ws_size) k >>= 1;
  unsigned short* Wt = (unsigned short*)alloc((size_t)k * C_ * DFF_ * 2);
  unsigned short* Xd = (unsigned short*)alloc((size_t)k * ROWS_PER_E * C_ * 2);
  unsigned short* Hb = (unsigned short*)alloc((size_t)k * ROWS_PER_E * DFF_ * 2);

  router_kernel<<<NTOK/4, 256, 0, stream>>>(x, Wg, bg, topk_e, topk_p);
  scan_kernel<<<B_, 256, 0, stream>>>(topk_e, pos_arr, slot_src, counts);

  for (int eb = 0; eb < E_; eb += k) {
    // W1 [C][DFF] -> Wt [DFF][C] bf16
    transpose_conv_kernel<<<dim3(DFF_/32, C_/32, k), 256, 0, stream>>>(
        W1 + (size_t)eb * C_ * DFF_, Wt, C_, DFF_);
    dispatch_kernel<<<(k * ROWS_PER_E) / 4, 256, 0, stream>>>(x, slot_src, counts, Xd, eb, k);
    // H = relu(Xd @ W1 + b1)
    {
      int nwg = k * (ROWS_PER_E/256) * (DFF_/256);
      gemm256_kernel<1><<<nwg, 512, 0, stream>>>(
          Xd, Wt, b1 + (size_t)eb * DFF_, Hb, ROWS_PER_E, DFF_, C_, nwg);
    }
    // W2 [DFF][C] -> Wt [C][DFF] bf16 (reuses Wt; stream-ordered after GEMM1)
    transpose_conv_kernel<<<dim3(C_/32, DFF_/32, k), 256, 0, stream>>>(
        W2 + (size_t)eb * DFF_ * C_, Wt, DFF_, C_);
    // Y = H @ W2 + b2
    {
      int nwg = k * (ROWS_PER_E/256) * (C_/256);
      gemm256_kernel<0><<<nwg, 512, 0, stream>>>(
          Hb, Wt, b2 + (size_t)eb * C_, Ybuf + (size_t)eb * ROWS_PER_E * C_, ROWS_PER_E, C_, DFF_, nwg);
    }
  }

  combine_kernel<<<NTOK/4, 256, 0, stream>>>(Ybuf, topk_e, topk_p, pos_arr, out);
}

// Round 4
// 587.952 us; speedup vs baseline: 1.1092x; 1.0403x over previous
//
#include <hip/hip_runtime.h>
#include <stdint.h>

#define B_ 8
#define T_ 2048
#define C_ 1024
#define E_ 8
#define K_ 2
#define CAP_ 320
#define DFF_ 4096
#define S_ (T_*K_)          // 4096 assignments per batch row
#define NTOK (B_*T_)        // 16384 tokens
#define ROWS_PER_E (B_*CAP_) // 2560

typedef __attribute__((ext_vector_type(8))) short short8;
typedef __attribute__((ext_vector_type(4))) float floatx4;

__device__ __forceinline__ unsigned short f2bf(float f) {
  union { float f; unsigned u; } v; v.f = f;
  unsigned r = v.u + 0x7fffu + ((v.u >> 16) & 1u);
  return (unsigned short)(r >> 16);
}
__device__ __forceinline__ float bf2f(unsigned short h) {
  union { unsigned u; float f; } v; v.u = ((unsigned)h) << 16;
  return v.f;
}

// async global->LDS, 16B per lane; LDS dest is wave-uniform base + lane*16
#define GLOAD16(g, l) __builtin_amdgcn_global_load_lds( \
    (const __attribute__((address_space(1))) void*)(g), \
    (__attribute__((address_space(3))) void*)(l), 16, 0, 0)

// ---------------- Router: fp64 logits, softmax, top-2 ----------------
__global__ void router_kernel(const float* __restrict__ x, const float* __restrict__ Wg,
                              const float* __restrict__ bg,
                              int* __restrict__ topk_e, float* __restrict__ topk_p)
{
  int token = (int)((blockIdx.x * blockDim.x + threadIdx.x) >> 6);
  int lane = threadIdx.x & 63;
  if (token >= NTOK) return;
  const float* xr = x + (size_t)token * C_;
  double acc[E_];
  #pragma unroll
  for (int e = 0; e < E_; ++e) acc[e] = 0.0;
  for (int c = lane; c < C_; c += 64) {
    double xv = (double)xr[c];
    const float4* w4 = (const float4*)(Wg + (size_t)c * E_);
    float4 wa = w4[0], wb = w4[1];
    acc[0] += xv * (double)wa.x; acc[1] += xv * (double)wa.y;
    acc[2] += xv * (double)wa.z; acc[3] += xv * (double)wa.w;
    acc[4] += xv * (double)wb.x; acc[5] += xv * (double)wb.y;
    acc[6] += xv * (double)wb.z; acc[7] += xv * (double)wb.w;
  }
  #pragma unroll
  for (int off = 32; off; off >>= 1) {
    #pragma unroll
    for (int e = 0; e < E_; ++e) acc[e] += __shfl_down(acc[e], off, 64);
  }
  if (lane == 0) {
    double lg[E_];
    double mx = -1e300;
    #pragma unroll
    for (int e = 0; e < E_; ++e) { lg[e] = acc[e] + (double)bg[e]; mx = fmax(mx, lg[e]); }
    double se = 0.0, pr[E_];
    #pragma unroll
    for (int e = 0; e < E_; ++e) { pr[e] = exp(lg[e] - mx); se += pr[e]; }
    #pragma unroll
    for (int e = 0; e < E_; ++e) pr[e] /= se;
    int e0 = 0;
    #pragma unroll
    for (int e = 1; e < E_; ++e) if (pr[e] > pr[e0]) e0 = e;
    int e1 = -1;
    #pragma unroll
    for (int e = 0; e < E_; ++e) {
      if (e == e0) continue;
      if (e1 < 0 || pr[e] > pr[e1]) e1 = e;
    }
    topk_e[token*2+0] = e0; topk_p[token*2+0] = (float)pr[e0];
    topk_e[token*2+1] = e1; topk_p[token*2+1] = (float)pr[e1];
  }
}

// ---------------- Scan: per-(b,e) positions, capacity, slot map ----------------
__global__ void scan_kernel(const int* __restrict__ topk_e,
                            int* __restrict__ pos_arr,   // [B_*S_], -1 if dropped
                            int* __restrict__ slot_src,  // [E_*B_*CAP_] -> src token t
                            int* __restrict__ counts)    // [E_*B_]
{
  const int b = blockIdx.x;
  const int tid = threadIdx.x;
  const int PT = S_ / 256; // 16
  __shared__ int cnt[256][E_];
  int e_loc[16];
  int local[E_];
  #pragma unroll
  for (int e = 0; e < E_; ++e) local[e] = 0;
  const int* te = topk_e + (size_t)b * S_;
  for (int j = 0; j < PT; ++j) {
    int e = te[tid*PT + j];
    e_loc[j] = e;
    local[e]++;
  }
  #pragma unroll
  for (int e = 0; e < E_; ++e) cnt[tid][e] = local[e];
  __syncthreads();
  if (tid < E_) {
    int run = 0;
    for (int i = 0; i < 256; ++i) { int v = cnt[i][tid]; cnt[i][tid] = run; run += v; }
    counts[tid*B_ + b] = run;   // counts[e][b]
  }
  __syncthreads();
  int base[E_];
  #pragma unroll
  for (int e = 0; e < E_; ++e) base[e] = cnt[tid][e];
  for (int j = 0; j < PT; ++j) {
    int e = e_loc[j];
    int p = base[e]++;
    int s = tid*PT + j;
    if (p < CAP_) {
      pos_arr[(size_t)b*S_ + s] = p;
      slot_src[((size_t)e*B_ + b)*CAP_ + p] = s >> 1;  // token t
    } else {
      pos_arr[(size_t)b*S_ + s] = -1;
    }
  }
}

// ---------------- Transpose + fp32->bf16: in [R][Cc] -> out [Cc][R], per expert ----------------
__global__ void transpose_conv_kernel(const float* __restrict__ in, unsigned short* __restrict__ out,
                                      int R, int Cc)
{
  __shared__ float tile[32][33];
  const int e = blockIdx.z;
  const float* ine = in + (size_t)e * R * Cc;
  unsigned short* oute = out + (size_t)e * R * Cc;
  const int c0 = blockIdx.x * 32, r0 = blockIdx.y * 32;
  const int tx = threadIdx.x & 7, ty = threadIdx.x >> 3;  // 8 x 32
  float4 v = *(const float4*)(ine + (size_t)(r0 + ty) * Cc + c0 + tx*4);
  tile[ty][tx*4+0] = v.x; tile[ty][tx*4+1] = v.y;
  tile[ty][tx*4+2] = v.z; tile[ty][tx*4+3] = v.w;
  __syncthreads();
  ushort4 o;
  o.x = f2bf(tile[tx*4+0][ty]);
  o.y = f2bf(tile[tx*4+1][ty]);
  o.z = f2bf(tile[tx*4+2][ty]);
  o.w = f2bf(tile[tx*4+3][ty]);
  *(ushort4*)(oute + (size_t)(c0 + ty) * R + r0 + tx*4) = o;
}

// ---------------- Dispatch: gather x rows into [nexp][B*CAP][C] bf16 ----------------
__global__ void dispatch_kernel(const float* __restrict__ x, const int* __restrict__ slot_src,
                                const int* __restrict__ counts, unsigned short* __restrict__ Xd,
                                int e_base, int nexp)
{
  int row = (int)((blockIdx.x * blockDim.x + threadIdx.x) >> 6);
  int lane = threadIdx.x & 63;
  int total = nexp * B_ * CAP_;
  if (row >= total) return;
  int el = row / (B_*CAP_);
  int rem = row - el*(B_*CAP_);
  int b = rem / CAP_, slot = rem - b*CAP_;
  int eg = e_base + el;
  int cnt = counts[eg*B_ + b]; if (cnt > CAP_) cnt = CAP_;
  unsigned short* orow = Xd + (size_t)row * C_;
  if (slot < cnt) {
    int t = slot_src[((size_t)eg*B_ + b)*CAP_ + slot];
    const float4* xr = (const float4*)(x + ((size_t)b*T_ + t)*C_);
    #pragma unroll
    for (int i = 0; i < C_/256; ++i) {
      float4 v = xr[i*64 + lane];
      ushort4 o;
      o.x = f2bf(v.x); o.y = f2bf(v.y); o.z = f2bf(v.z); o.w = f2bf(v.w);
      ((ushort4*)orow)[i*64 + lane] = o;
    }
  } else {
    ushort4 z; z.x = z.y = z.z = z.w = 0;
    #pragma unroll
    for (int i = 0; i < C_/256; ++i) ((ushort4*)orow)[i*64 + lane] = z;
  }
}

// ---------------- GEMM 256x256, BK=32, ring-4 LDS, counted-vmcnt deep pipeline, T2 swizzle ----
// A [e][M][Kfull] bf16 x BT [e][N][Kfull] bf16 (+bias if non-null, opt relu) -> Out [e][M][N] bf16
// 512 threads = 8 waves (2M x 4N), per-wave 128x64 output. Ring of 4 K-tile slots
// (32KB each), prefetch 3 tiles ahead, counted vmcnt. LDS bank-conflict fix:
// involution kbyte ^= ((row>>1)&3)<<4 applied to BOTH the global staging source
// k-offset and the ds_read offsets (LDS dest stays linear; rule #21).
// Split-K: grid = nsplit * E*MT*NT blocks; split sp covers K [sp*klen, (sp+1)*klen),
// writes to Out0 (sp=0) or Out1 (sp=1).
template<int RELU>
__global__ __launch_bounds__(512) void gemm256_kernel(
    const unsigned short* __restrict__ A,
    const unsigned short* __restrict__ BT,
    const float* __restrict__ bias,      // [e][N] or nullptr
    unsigned short* __restrict__ Out0,
    unsigned short* __restrict__ Out1,
    int M, int N, int Kfull, int klen, int tilesPerSplit, int nwg)
{
  __shared__ __align__(16) unsigned short lds[4*16384]; // 128 KiB
  const int NT = N >> 8, MT = M >> 8;
  const int bid = blockIdx.x;
  // bijective XCD swizzle (nwg % 8 == 0 for all launch configs here)
  const int wg = (bid & 7) * (nwg >> 3) + (bid >> 3);
  const int sp  = wg / tilesPerSplit;
  const int wgr = wg - sp * tilesPerSplit;
  const int e  = wgr / (MT*NT);
  const int r2 = wgr - e*(MT*NT);
  const int mt = r2 / NT, nt = r2 - mt*NT;
  const int k0 = sp * klen;
  const unsigned short* Ae = A + (size_t)e * M * Kfull;
  const unsigned short* Be = BT + (size_t)e * N * Kfull;
  const float* be = bias ? (bias + (size_t)e * N) : nullptr;
  unsigned short* Oe = (sp == 0 ? Out0 : Out1) + (size_t)e * M * N;
  const int m0 = mt*256, n0 = nt*256;

  const int tid = threadIdx.x, lane = tid & 63, w = tid >> 6;
  const int wr = w >> 2, wc = w & 3;   // 2 x 4 waves

  floatx4 acc[8][4];
  #pragma unroll
  for (int i = 0; i < 8; ++i)
    #pragma unroll
    for (int j = 0; j < 4; ++j) acc[i][j] = (floatx4){0.f, 0.f, 0.f, 0.f};

  // staging decode: per matrix-tile 1024 chunks of 16B; thread covers chunks tid, 512+tid.
  // chunk c -> row c>>2, LDS k-slot (c&3)*8 shorts. Pre-swizzled global source:
  // src k-off = slot ^ swz(row), swz(row) = ((row>>1)&3)<<3 (shorts).
  const int c0 = tid, c1 = 512 + tid;
  const int sr0 = c0 >> 2, sr1 = c1 >> 2;
  const int sq0 = ((c0 & 3) * 8) ^ (((sr0 >> 1) & 3) << 3);
  const int sq1 = ((c1 & 3) * 8) ^ (((sr1 >> 1) & 3) << 3);
  const unsigned short* gA0 = Ae + (size_t)(m0 + sr0)*Kfull + k0 + sq0;
  const unsigned short* gA1 = Ae + (size_t)(m0 + sr1)*Kfull + k0 + sq1;
  const unsigned short* gB0 = Be + (size_t)(n0 + sr0)*Kfull + k0 + sq0;
  const unsigned short* gB1 = Be + (size_t)(n0 + sr1)*Kfull + k0 + sq1;
  const int ldsOff0 = w*512;          // shorts (wave-uniform), q=0 call
  const int ldsOff1 = 4096 + w*512;   // q=1 call

  // fragment read bases (per lane), with the same XOR on the k-offset.
  // swz is invariant under row += mf*16 (touches row bits >=4 only), so the
  // mf*512 / nf*512 read strides remain valid.
  const int fr = lane & 15, kq = lane >> 4;
  const int aRow = wr*128 + fr;
  const int bRow = wc*64 + fr;
  const int aOff = aRow*32 + ((kq*8) ^ (((aRow >> 1) & 3) << 3));
  const int bOff = 8192 + bRow*32 + ((kq*8) ^ (((bRow >> 1) & 3) << 3));

  const int nk = klen >> 5;

#define STAGE_A(t, slot) do { \
    GLOAD16(gA0 + (size_t)(t)*32, lds + (slot)*16384 + ldsOff0); \
    GLOAD16(gA1 + (size_t)(t)*32, lds + (slot)*16384 + ldsOff1); } while(0)
#define STAGE_B(t, slot) do { \
    GLOAD16(gB0 + (size_t)(t)*32, lds + (slot)*16384 + 8192 + ldsOff0); \
    GLOAD16(gB1 + (size_t)(t)*32, lds + (slot)*16384 + 8192 + ldsOff1); } while(0)

  // prologue: stage tiles 0,1,2 into slots 0,1,2 (12 loads/thread)
  STAGE_A(0, 0); STAGE_B(0, 0);
  STAGE_A(1, 1); STAGE_B(1, 1);
  STAGE_A(2, 2); STAGE_B(2, 2);
  asm volatile("s_waitcnt vmcnt(8)" ::: "memory");   // tile 0 landed
  __builtin_amdgcn_s_barrier();

  for (int t = 0; t < nk; ++t) {
    const int slot = t & 3, ps = (t + 3) & 3;
    const unsigned short* sT = lds + slot*16384;
    const bool pf = (t + 3 < nk);
    short8 bfr[4], af[4];

    // ---- phase 1: B frags + A frags(mf0-3) | stage A(t+3) | MFMA quadrant 1 ----
    #pragma unroll
    for (int nf = 0; nf < 4; ++nf) bfr[nf] = *(const short8*)(sT + bOff + nf*512);
    #pragma unroll
    for (int mf = 0; mf < 4; ++mf) af[mf] = *(const short8*)(sT + aOff + mf*512);
    if (pf) STAGE_A(t+3, ps);
    __builtin_amdgcn_s_barrier();
    asm volatile("s_waitcnt lgkmcnt(0)" ::: "memory");
    __builtin_amdgcn_sched_barrier(0);
    __builtin_amdgcn_s_setprio(1);
    #pragma unroll
    for (int mf = 0; mf < 4; ++mf)
      #pragma unroll
      for (int nf = 0; nf < 4; ++nf)
        acc[mf][nf] = __builtin_amdgcn_mfma_f32_16x16x32_bf16(af[mf], bfr[nf], acc[mf][nf], 0, 0, 0);
    __builtin_amdgcn_s_setprio(0);
    __builtin_amdgcn_sched_barrier(0);
    __builtin_amdgcn_s_barrier();

    // ---- phase 2: A frags(mf4-7) | stage B(t+3) | MFMA quadrant 2 ----
    #pragma unroll
    for (int mf = 0; mf < 4; ++mf) af[mf] = *(const short8*)(sT + aOff + (mf+4)*512);
    if (pf) STAGE_B(t+3, ps);
    __builtin_amdgcn_s_barrier();
    asm volatile("s_waitcnt lgkmcnt(0)" ::: "memory");
    __builtin_amdgcn_sched_barrier(0);
    __builtin_amdgcn_s_setprio(1);
    #pragma unroll
    for (int mf = 0; mf < 4; ++mf)
      #pragma unroll
      for (int nf = 0; nf < 4; ++nf)
        acc[mf+4][nf] = __builtin_amdgcn_mfma_f32_16x16x32_bf16(af[mf], bfr[nf], acc[mf+4][nf], 0, 0, 0);
    __builtin_amdgcn_s_setprio(0);
    __builtin_amdgcn_sched_barrier(0);

    // tile boundary: publish tile t+1 (counted wait, never 0 until tail)
    if (t + 1 < nk) {
      if (t + 3 < nk)      asm volatile("s_waitcnt vmcnt(8)" ::: "memory");
      else if (t + 2 < nk) asm volatile("s_waitcnt vmcnt(4)" ::: "memory");
      else                 asm volatile("s_waitcnt vmcnt(0)" ::: "memory");
      __builtin_amdgcn_s_barrier();
    }
  }
#undef STAGE_A
#undef STAGE_B

  // epilogue: C/D layout col = lane&15, row = (lane>>4)*4 + reg
  const int col = lane & 15, rbase = (lane >> 4) * 4;
  #pragma unroll
  for (int mf = 0; mf < 8; ++mf) {
    const int gr0 = m0 + wr*128 + mf*16 + rbase;
    #pragma unroll
    for (int nf = 0; nf < 4; ++nf) {
      const int gc = n0 + wc*64 + nf*16 + col;
      const float bv = be ? be[gc] : 0.f;
      #pragma unroll
      for (int r = 0; r < 4; ++r) {
        float v = acc[mf][nf][r] + bv;
        if (RELU) v = fmaxf(v, 0.f);
        Oe[(size_t)(gr0 + r)*N + gc] = f2bf(v);
      }
    }
  }
}

// ---------------- Combine: out[b,t] = sum_k p_k * (Y0 + Y1 + b2)[e_k, b, pos_k] ----------------
__global__ void combine_kernel(const unsigned short* __restrict__ Y0, // [E][B*CAP][C] bf16
                               const unsigned short* __restrict__ Y1, // split-1 partial or null
                               const float* __restrict__ b2c,         // [E][C] or null
                               const int* __restrict__ topk_e, const float* __restrict__ topk_p,
                               const int* __restrict__ pos_arr, float* __restrict__ out)
{
  int token = (int)((blockIdx.x * blockDim.x + threadIdx.x) >> 6);
  int lane = threadIdx.x & 63;
  if (token >= NTOK) return;
  int b = token / T_, t = token - b*T_;
  int s0 = b*S_ + t*2;
  float acc[16];
  #pragma unroll
  for (int i = 0; i < 16; ++i) acc[i] = 0.f;
  #pragma unroll
  for (int k = 0; k < 2; ++k) {
    int pos = pos_arr[s0 + k];
    if (pos < 0) continue;
    int e = topk_e[s0 + k];
    float p = topk_p[s0 + k];
    size_t rowoff = (((size_t)e*B_ + b)*CAP_ + pos) * C_;
    const unsigned short* yr0 = Y0 + rowoff;
    const unsigned short* yr1 = Y1 ? (Y1 + rowoff) : nullptr;
    const float* bb = b2c ? (b2c + (size_t)e * C_) : nullptr;
    #pragma unroll
    for (int i = 0; i < 4; ++i) {
      ushort4 v = ((const ushort4*)yr0)[i*64 + lane];
      float s0v = bf2f(v.x), s1v = bf2f(v.y), s2v = bf2f(v.z), s3v = bf2f(v.w);
      if (yr1) {
        ushort4 u = ((const ushort4*)yr1)[i*64 + lane];
        s0v += bf2f(u.x); s1v += bf2f(u.y); s2v += bf2f(u.z); s3v += bf2f(u.w);
      }
      if (bb) {
        float4 bv = ((const float4*)bb)[i*64 + lane];
        s0v += bv.x; s1v += bv.y; s2v += bv.z; s3v += bv.w;
      }
      acc[i*4+0] += p * s0v;
      acc[i*4+1] += p * s1v;
      acc[i*4+2] += p * s2v;
      acc[i*4+3] += p * s3v;
    }
  }
  float4* orow = (float4*)(out + (size_t)token * C_);
  #pragma unroll
  for (int i = 0; i < 4; ++i) {
    float4 o;
    o.x = acc[i*4+0]; o.y = acc[i*4+1]; o.z = acc[i*4+2]; o.w = acc[i*4+3];
    orow[i*64 + lane] = o;
  }
}

extern "C" void kernel_launch(void* const* d_in, const int* in_sizes, int n_in,
                              void* d_out, int out_size, void* d_ws, size_t ws_size,
                              hipStream_t stream)
{
  const float* x  = (const float*)d_in[0];
  const float* Wg = (const float*)d_in[1];
  const float* bg = (const float*)d_in[2];
  const float* W1 = (const float*)d_in[3];
  const float* b1 = (const float*)d_in[4];
  const float* W2 = (const float*)d_in[5];
  const float* b2 = (const float*)d_in[6];
  float* out = (float*)d_out;

  char* ws = (char*)d_ws;
  size_t off = 0;
  auto alloc = [&](size_t bytes) -> char* {
    char* p = ws + off;
    off = (off + bytes + 255) & ~(size_t)255;
    return p;
  };
  int*   topk_e  = (int*)  alloc((size_t)NTOK * K_ * 4);
  float* topk_p  = (float*)alloc((size_t)NTOK * K_ * 4);
  int*   pos_arr = (int*)  alloc((size_t)B_ * S_ * 4);
  int*   slot_src= (int*)  alloc((size_t)E_ * B_ * CAP_ * 4);
  int*   counts  = (int*)  alloc((size_t)E_ * B_ * 4);
  unsigned short* Ybuf = (unsigned short*)alloc((size_t)E_ * ROWS_PER_E * C_ * 2);
  size_t fixed = off;
  const size_t perE = (size_t)C_ * DFF_ * 2      // W^T
                    + (size_t)ROWS_PER_E * C_ * 2  // Xdisp
                    + (size_t)ROWS_PER_E * DFF_ * 2 // H
                    + 3 * 256;
  int k = 8;
  while (k > 1 && fixed + (size_t)k * perE > ws_size) k >>= 1;
  unsigned short* Wt = (unsigned short*)alloc((size_t)k * C_ * DFF_ * 2);
  unsigned short* Xd = (unsigned short*)alloc((size_t)k * ROWS_PER_E * C_ * 2);
  unsigned short* Hb = (unsigned short*)alloc((size_t)k * ROWS_PER_E * DFF_ * 2);

  router_kernel<<<NTOK/4, 256, 0, stream>>>(x, Wg, bg, topk_e, topk_p);
  scan_kernel<<<B_, 256, 0, stream>>>(topk_e, pos_arr, slot_src, counts);

  const bool splitK2 = (k == 8);  // split-1 output reuses Xd (exactly Y-sized at k=8)

  for (int eb = 0; eb < E_; eb += k) {
    // W1 [C][DFF] -> Wt [DFF][C] bf16
    transpose_conv_kernel<<<dim3(DFF_/32, C_/32, k), 256, 0, stream>>>(
        W1 + (size_t)eb * C_ * DFF_, Wt, C_, DFF_);
    dispatch_kernel<<<(k * ROWS_PER_E) / 4, 256, 0, stream>>>(x, slot_src, counts, Xd, eb, k);
    // H = relu(Xd @ W1 + b1)
    {
      int tiles = k * (ROWS_PER_E/256) * (DFF_/256);
      gemm256_kernel<1><<<tiles, 512, 0, stream>>>(
          Xd, Wt, b1 + (size_t)eb * DFF_, Hb, Hb, ROWS_PER_E, DFF_, C_, C_, tiles, tiles);
    }
    // W2 [DFF][C] -> Wt [C][DFF] bf16 (reuses Wt; stream-ordered after GEMM1)
    transpose_conv_kernel<<<dim3(C_/32, DFF_/32, k), 256, 0, stream>>>(
        W2 + (size_t)eb * DFF_ * C_, Wt, DFF_, C_);
    // Y = H @ W2 (+ b2 here only if not split; in split mode combine adds b2)
    {
      int tiles = k * (ROWS_PER_E/256) * (C_/256);
      if (splitK2) {
        gemm256_kernel<0><<<2*tiles, 512, 0, stream>>>(
            Hb, Wt, nullptr, Ybuf, Xd, ROWS_PER_E, C_, DFF_, DFF_/2, tiles, 2*tiles);
      } else {
        gemm256_kernel<0><<<tiles, 512, 0, stream>>>(
            Hb, Wt, b2 + (size_t)eb * C_, Ybuf + (size_t)eb * ROWS_PER_E * C_,
            Ybuf + (size_t)eb * ROWS_PER_E * C_, ROWS_PER_E, C_, DFF_, DFF_, tiles, tiles);
      }
    }
  }

  combine_kernel<<<NTOK/4, 256, 0, stream>>>(
      Ybuf, splitK2 ? Xd : nullptr, splitK2 ? b2 : nullptr,
      topk_e, topk_p, pos_arr, out);
}